// Round 7
// baseline (291.267 us; speedup 1.0000x reference)
//
#include <hip/hip_runtime.h>
#include <hip/hip_bf16.h>

using bf16 = __hip_bfloat16;
typedef __attribute__((ext_vector_type(8))) short shortx8;  // 8 bf16 = 4 VGPRs (MFMA A/B frag)
typedef __attribute__((ext_vector_type(4))) float f32x4;    // MFMA C/D frag

#define SEQ 8192
#define DM 1024
#define NH 16
#define CHUNK 64
#define NC (SEQ / CHUNK)   // 128

// async global->LDS, 16B per lane; LDS dest is wave-uniform base + lane*16
__device__ __forceinline__ void load_lds16(const bf16* g, bf16* l) {
    __builtin_amdgcn_global_load_lds(
        (const __attribute__((address_space(1))) void*)g,
        (__attribute__((address_space(3))) void*)l, 16, 0, 0);
}

__device__ __forceinline__ float bf2f(short s) {
    union { unsigned u; float f; } x;
    x.u = ((unsigned)(unsigned short)s) << 16;
    return x.f;
}

// ---------------------------------------------------------------------------
// One-shot fp32 -> bf16 conversion for xs + 4 weight matrices.
// Weight outputs contiguous in wall: wk|wv|w1|w2.
// ---------------------------------------------------------------------------
#define XS_G ((size_t)SEQ * DM / 4)      // 2,097,152
#define W_G  ((size_t)DM * DM / 4)       // 262,144
__global__ __launch_bounds__(256) void convert_all(const float* __restrict__ xs,
                                                   const float* __restrict__ wk,
                                                   const float* __restrict__ wv,
                                                   const float* __restrict__ w1,
                                                   const float* __restrict__ w2,
                                                   bf16* __restrict__ xsb,
                                                   bf16* __restrict__ wall) {
    size_t g = (size_t)blockIdx.x * 256 + threadIdx.x;
    const float* in;
    bf16* out;
    size_t off;
    if (g < XS_G) {
        in = xs; out = xsb; off = g;
    } else {
        size_t r = g - XS_G;
        int w = (int)(r / W_G);
        off = r % W_G;
        const float* ws[4] = {wk, wv, w1, w2};
        in = ws[w];
        out = wall + (size_t)w * DM * DM;
    }
    size_t i = off * 4;
    float4 f = *(const float4*)(in + i);
    out[i + 0] = __float2bfloat16(f.x);
    out[i + 1] = __float2bfloat16(f.y);
    out[i + 2] = __float2bfloat16(f.z);
    out[i + 3] = __float2bfloat16(f.w);
}

// ---------------------------------------------------------------------------
// NT GEMM: C[SEQ,DM] = A[SEQ,DM]*B[DM,DM]^T, bf16 in, fp32 acc. 128x128 tile,
// BK=64, 4 waves x (4x4 mfma_f32_16x16x32_bf16). global_load_lds(16B) staging
// into UNPADDED LDS [128][64]; bank conflicts broken by XOR swizzle (applied
// to the global source address; LDS dest stays linear as global_load_lds
// needs). K is COMPILE-TIME: staging base pointers hoisted, K-loop fully
// unrolled so every global_load_lds / ds_read address is base+imm (folds into
// the 13-bit offset field -> no per-iteration address VALU).
// XCD swizzle: blocks sharing an A row-tile satisfy L==ry (mod 8) -> same XCD.
// MODE 0: K proj — act=elu+1, reduce over d -> kappa[h][t]; NO C write
// MODE 1: V proj — bf16 C + fused per-(chunk,head) num/den sums (each wave's
//         64x64 subtile is exactly one chunk x one head)
// MODE 2: MLP1   — +bias, tanh-gelu -> bf16
// MODE 3: MLP2   — +bias -> fp32 (final output)
// ---------------------------------------------------------------------------
template <int MODE>
__global__ __launch_bounds__(256) void gemm_nt(const bf16* __restrict__ A,
                                               const bf16* __restrict__ B,
                                               void* __restrict__ Cv,
                                               const float* __restrict__ bias,
                                               float* __restrict__ kappa,
                                               float* __restrict__ numbuf,
                                               float* __restrict__ denbuf) {
    constexpr int K = DM;   // 1024
    constexpr int N = DM;   // 1024
    __shared__ bf16 As[128][64];
    __shared__ bf16 Bs[128][64];
    __shared__ float Ksh[4][64];   // MODE 1 only (1KB)

    const int tid  = threadIdx.x;
    // XCD swizzle: L = bx + by*gridX; rx = L / gridY, ry = L % gridY
    const int L    = blockIdx.x + blockIdx.y * gridDim.x;
    const int ry   = L % gridDim.y;
    const int rx   = L / gridDim.y;
    const int bm   = ry * 128;
    const int bn   = rx * 128;
    const int wave = tid >> 6;
    const int lane = tid & 63;
    const int wm   = (wave >> 1) * 64;
    const int wn   = (wave & 1) * 64;
    const int quad = lane >> 4;
    const int m16  = lane & 15;
    const int r7   = m16 & 7;

    f32x4 acc[4][4];
    #pragma unroll
    for (int i = 0; i < 4; ++i)
        #pragma unroll
        for (int j = 0; j < 4; ++j)
            #pragma unroll
            for (int r = 0; r < 4; ++r) acc[i][j][r] = 0.f;

    // hoisted staging addresses: slot s=(it*256+tid) covers (row=s>>3, pos=s&7);
    // global group g = pos^(row&7) so LDS position pos holds it (XOR swizzle)
    const bf16* gA[4];
    const bf16* gB[4];
    bf16* lA[4];
    bf16* lB[4];
    #pragma unroll
    for (int it = 0; it < 4; ++it) {
        int s = it * 256 + tid;
        int row = s >> 3, pos = s & 7;
        int g = pos ^ (row & 7);
        gA[it] = A + (size_t)(bm + row) * K + g * 8;
        gB[it] = B + (size_t)(bn + row) * K + g * 8;
        lA[it] = &As[row][pos * 8];
        lB[it] = &Bs[row][pos * 8];
    }

    #pragma unroll
    for (int k0 = 0; k0 < K; k0 += 64) {   // fully unrolled: 16 iterations
        #pragma unroll
        for (int it = 0; it < 4; ++it) {
            load_lds16(gA[it] + k0, lA[it]);   // base + imm offset (<=1920 B)
            load_lds16(gB[it] + k0, lB[it]);
        }
        __syncthreads();

        #pragma unroll
        for (int kx = 0; kx < 2; ++kx) {
            const int p = ((kx << 2) + quad) ^ r7;
            shortx8 af[4], bfr[4];
            #pragma unroll
            for (int i = 0; i < 4; ++i)
                af[i] = *(const shortx8*)&As[wm + i * 16 + m16][p * 8];
            #pragma unroll
            for (int j = 0; j < 4; ++j)
                bfr[j] = *(const shortx8*)&Bs[wn + j * 16 + m16][p * 8];
            #pragma unroll
            for (int i = 0; i < 4; ++i)
                #pragma unroll
                for (int j = 0; j < 4; ++j)
                    acc[i][j] = __builtin_amdgcn_mfma_f32_16x16x32_bf16(af[i], bfr[j], acc[i][j], 0, 0, 0);
        }
        __syncthreads();
    }

    if (MODE == 0) {
        // kappa[h][t] = sum_d act(K[t][h*64+d]); wave subtile covers head h fully
        const int h = (bn + wn) >> 6;
        #pragma unroll
        for (int i = 0; i < 4; ++i) {
            #pragma unroll
            for (int r = 0; r < 4; ++r) {
                float s = 0.f;
                #pragma unroll
                for (int j = 0; j < 4; ++j) {
                    float v = acc[i][j][r];
                    s += v > 0.f ? v + 1.f : __expf(v);
                }
                s += __shfl_xor(s, 1);
                s += __shfl_xor(s, 2);
                s += __shfl_xor(s, 4);
                s += __shfl_xor(s, 8);
                if (m16 == 0)
                    kappa[(size_t)h * SEQ + bm + wm + i * 16 + quad * 4 + r] = s;
            }
        }
        return;
    }

    if (MODE == 1) {
        // wave's subtile = chunk c (rows) x head h (cols), both complete
        const int c = (bm + wm) >> 6;
        const int h = (bn + wn) >> 6;
        float kv = kappa[(size_t)h * SEQ + bm + wm + lane];
        Ksh[wave][lane] = kv;       // wave-private LDS row, no barrier needed
        float dsum = kv;
        #pragma unroll
        for (int off = 32; off > 0; off >>= 1) dsum += __shfl_xor(dsum, off);
        if (lane == 0) denbuf[(size_t)h * NC + c] = dsum;

        float s[4] = {0.f, 0.f, 0.f, 0.f};
        #pragma unroll
        for (int i = 0; i < 4; ++i) {
            #pragma unroll
            for (int r = 0; r < 4; ++r) {
                float kr = Ksh[wave][i * 16 + quad * 4 + r];
                #pragma unroll
                for (int j = 0; j < 4; ++j) s[j] += kr * acc[i][j][r];
            }
        }
        #pragma unroll
        for (int j = 0; j < 4; ++j) {
            s[j] += __shfl_xor(s[j], 16);
            s[j] += __shfl_xor(s[j], 32);
        }
        if (quad == 0) {
            size_t nb = ((size_t)h * NC + c) * 64;
            #pragma unroll
            for (int j = 0; j < 4; ++j) numbuf[nb + j * 16 + m16] = s[j];
        }
        // fall through to bf16 V store
    }

    // C/D layout: col = lane&15, row = quad*4 + reg (verified m89/m91)
    #pragma unroll
    for (int i = 0; i < 4; ++i) {
        int row0 = bm + wm + i * 16 + quad * 4;
        #pragma unroll
        for (int j = 0; j < 4; ++j) {
            int col = bn + wn + j * 16 + m16;
            #pragma unroll
            for (int r = 0; r < 4; ++r) {
                float v = acc[i][j][r];
                size_t o = (size_t)(row0 + r) * N + col;
                if (MODE == 1) {
                    ((bf16*)Cv)[o] = __float2bfloat16(v);
                } else if (MODE == 2) {
                    v += bias[col];
                    float t = tanhf(0.7978845608028654f * (v + 0.044715f * v * v * v));
                    ((bf16*)Cv)[o] = __float2bfloat16(0.5f * v * (1.f + t));
                } else {
                    v += bias[col];
                    ((float*)Cv)[o] = v;
                }
            }
        }
    }
}

// ---------------------------------------------------------------------------
// Exclusive prefix over chunks, parallel: one block per head, wave w owns
// chunks [w*32, w*32+32) in registers; cross-wave offsets via LDS.
// ---------------------------------------------------------------------------
__global__ __launch_bounds__(256) void prefix_state(float* __restrict__ numbuf,
                                                    float* __restrict__ denbuf) {
    const int h = blockIdx.x;
    const int wave = threadIdx.x >> 6;
    const int d = threadIdx.x & 63;
    __shared__ float tot[4][64];
    __shared__ float dtot[4];

    float val[32], dval[32];
    const int c0 = wave * 32;
    #pragma unroll
    for (int i = 0; i < 32; ++i) {
        size_t idx = (size_t)h * NC + c0 + i;
        val[i]  = numbuf[idx * 64 + d];
        dval[i] = denbuf[idx];          // broadcast load, all lanes same
    }
    float run = 0.f, drun = 0.f;
    #pragma unroll
    for (int i = 0; i < 32; ++i) {
        float t = val[i];  val[i]  = run;  run  += t;
        float dt = dval[i]; dval[i] = drun; drun += dt;
    }
    tot[wave][d] = run;
    if (d == 0) dtot[wave] = drun;
    __syncthreads();
    float off = 0.f, doff = 0.f;
    for (int w = 0; w < wave; ++w) { off += tot[w][d]; doff += dtot[w]; }
    #pragma unroll
    for (int i = 0; i < 32; ++i) {
        size_t idx = (size_t)h * NC + c0 + i;
        numbuf[idx * 64 + d] = val[i] + off;
        if (d == 0) denbuf[idx] = dval[i] + doff;
    }
}

// ---------------------------------------------------------------------------
// out[t][v] = (Nexcl[v] + sum_{i<=t} kappa_i V[i][v]) / (Dexcl + sum_{i<=t} kappa_i)
// Thread (t = tid>>2, v0 = (tid&3)*16) owns 16 outputs. V is bf16.
// ---------------------------------------------------------------------------
__global__ __launch_bounds__(256) void chunk_out(const bf16* __restrict__ vb,
                                                 const float* __restrict__ kappa,
                                                 const float* __restrict__ numbuf,
                                                 const float* __restrict__ denbuf,
                                                 bf16* __restrict__ out) {
    const int h = blockIdx.x, c = blockIdx.y;
    __shared__ float Ksh[64];
    __shared__ float Vs[64][64];
    const int tid = threadIdx.x;

    #pragma unroll
    for (int it = 0; it < 2; ++it) {
        int s = it * 256 + tid;
        int r = s >> 3, d8 = (s & 7) * 8;
        shortx8 raw = *(const shortx8*)(vb + (size_t)(c * 64 + r) * DM + h * 64 + d8);
        #pragma unroll
        for (int e = 0; e < 8; ++e) Vs[r][d8 + e] = bf2f(raw[e]);
    }
    if (tid < 64) Ksh[tid] = kappa[(size_t)h * SEQ + c * 64 + tid];
    __syncthreads();

    const int t  = tid >> 2;
    const int v0 = (tid & 3) << 4;
    const size_t bidx = (size_t)h * NC + c;

    float den = denbuf[bidx];
    float num[16];
    #pragma unroll
    for (int jj = 0; jj < 4; ++jj) {
        float4 n4 = *(const float4*)&numbuf[bidx * 64 + v0 + jj * 4];
        num[jj * 4 + 0] = n4.x; num[jj * 4 + 1] = n4.y;
        num[jj * 4 + 2] = n4.z; num[jj * 4 + 3] = n4.w;
    }

    for (int i = 0; i <= t; ++i) {
        float s = Ksh[i];
        den += s;
        #pragma unroll
        for (int jj = 0; jj < 4; ++jj) {
            float4 v4 = *(const float4*)&Vs[i][v0 + jj * 4];
            num[jj * 4 + 0] += s * v4.x; num[jj * 4 + 1] += s * v4.y;
            num[jj * 4 + 2] += s * v4.z; num[jj * 4 + 3] += s * v4.w;
        }
    }

    const float inv = 1.0f / den;
    size_t og = (size_t)(c * 64 + t) * DM + h * 64 + v0;
    #pragma unroll
    for (int j = 0; j < 16; ++j) out[og + j] = __float2bfloat16(num[j] * inv);
}

// ---------------------------------------------------------------------------
extern "C" void kernel_launch(void* const* d_in, const int* in_sizes, int n_in,
                              void* d_out, int out_size, void* d_ws, size_t ws_size,
                              hipStream_t stream) {
    const float* xs = (const float*)d_in[0];
    // d_in[1] = wq — provably unused: 'hkv,hq->hv' / 'hk,hq->h' sum k and q
    // independently, so the Sum(qa) factor cancels in sq/zq.
    const float* wk = (const float*)d_in[2];
    const float* wv = (const float*)d_in[3];
    const float* w1 = (const float*)d_in[4];
    const float* b1 = (const float*)d_in[5];
    const float* w2 = (const float*)d_in[6];
    const float* b2 = (const float*)d_in[7];
    float* y = (float*)d_out;

    char* base = (char*)d_ws;
    size_t off = 0;
    auto alloc = [&](size_t b) -> char* {
        char* p = base + off;
        off += (b + 255) & ~(size_t)255;
        return p;
    };

    const size_t NMAT = (size_t)SEQ * DM;      // 8.39M
    const size_t NW   = (size_t)DM * DM;       // 1.05M
    bf16*  xsb    = (bf16*)alloc(NMAT * 2);
    bf16*  wall   = (bf16*)alloc(4 * NW * 2);  // wk|wv|w1|w2, contiguous
    bf16*  wkb    = wall;
    bf16*  wvb    = wall + NW;
    bf16*  w1b    = wall + 2 * NW;
    bf16*  w2b    = wall + 3 * NW;
    bf16*  vb     = (bf16*)alloc(NMAT * 2);    // V bf16
    float* kappa  = (float*)alloc((size_t)NH * SEQ * 4);
    float* numbuf = (float*)alloc((size_t)NH * NC * 64 * 4);
    float* denbuf = (float*)alloc((size_t)NH * NC * 4);
    bf16*  outb   = (bf16*)alloc(NMAT * 2);
    bf16*  hb     = (bf16*)alloc(NMAT * 2);

    // 1. all conversions in one launch (wq skipped)
    {
        size_t total_g = XS_G + 4 * W_G;       // 3,145,728 vec4 groups
        convert_all<<<(int)(total_g / 256), 256, 0, stream>>>(xs, wk, wv, w1, w2,
                                                              xsb, wall);
    }

    // 2. K projection (act + kappa reduction fused, no K stored), then
    //    V projection (bf16 V + fused per-chunk num/den sums)
    dim3 ggrid(DM / 128, SEQ / 128);   // (8, 64)
    gemm_nt<0><<<ggrid, 256, 0, stream>>>(xsb, wkb, nullptr, nullptr, kappa,
                                          nullptr, nullptr);
    gemm_nt<1><<<ggrid, 256, 0, stream>>>(xsb, wvb, vb, nullptr, kappa,
                                          numbuf, denbuf);

    // 3. exclusive chunk prefix + per-token output
    prefix_state<<<NH, 256, 0, stream>>>(numbuf, denbuf);
    chunk_out<<<dim3(NH, NC), 256, 0, stream>>>(vb, kappa, numbuf, denbuf, outb);

    // 4. MLP
    gemm_nt<2><<<ggrid, 256, 0, stream>>>(outb, w1b, hb, b1, nullptr,
                                          nullptr, nullptr);
    gemm_nt<3><<<ggrid, 256, 0, stream>>>(hb, w2b, y, b2, nullptr,
                                          nullptr, nullptr);
}

// Round 8
// 241.953 us; speedup vs baseline: 1.2038x; 1.2038x over previous
//
#include <hip/hip_runtime.h>
#include <hip/hip_bf16.h>

using bf16 = __hip_bfloat16;
typedef __attribute__((ext_vector_type(8))) short shortx8;  // 8 bf16 = 4 VGPRs (MFMA A/B frag)
typedef __attribute__((ext_vector_type(4))) float f32x4;    // MFMA C/D frag

#define SEQ 8192
#define DM 1024
#define NH 16
#define CHUNK 64
#define NC (SEQ / CHUNK)   // 128

// async global->LDS, 16B per lane; LDS dest is wave-uniform base + lane*16
__device__ __forceinline__ void load_lds16(const bf16* g, bf16* l) {
    __builtin_amdgcn_global_load_lds(
        (const __attribute__((address_space(1))) void*)g,
        (__attribute__((address_space(3))) void*)l, 16, 0, 0);
}

__device__ __forceinline__ float bf2f(short s) {
    union { unsigned u; float f; } x;
    x.u = ((unsigned)(unsigned short)s) << 16;
    return x.f;
}

// ---------------------------------------------------------------------------
// One-shot fp32 -> bf16 conversion for xs + 4 weight matrices.
// Weight outputs contiguous in wall: wk|wv|w1|w2.
// ---------------------------------------------------------------------------
#define XS_G ((size_t)SEQ * DM / 4)      // 2,097,152
#define W_G  ((size_t)DM * DM / 4)       // 262,144
__global__ __launch_bounds__(256) void convert_all(const float* __restrict__ xs,
                                                   const float* __restrict__ wk,
                                                   const float* __restrict__ wv,
                                                   const float* __restrict__ w1,
                                                   const float* __restrict__ w2,
                                                   bf16* __restrict__ xsb,
                                                   bf16* __restrict__ wall) {
    size_t g = (size_t)blockIdx.x * 256 + threadIdx.x;
    const float* in;
    bf16* out;
    size_t off;
    if (g < XS_G) {
        in = xs; out = xsb; off = g;
    } else {
        size_t r = g - XS_G;
        int w = (int)(r / W_G);
        off = r % W_G;
        const float* ws[4] = {wk, wv, w1, w2};
        in = ws[w];
        out = wall + (size_t)w * DM * DM;
    }
    size_t i = off * 4;
    float4 f = *(const float4*)(in + i);
    out[i + 0] = __float2bfloat16(f.x);
    out[i + 1] = __float2bfloat16(f.y);
    out[i + 2] = __float2bfloat16(f.z);
    out[i + 3] = __float2bfloat16(f.w);
}

// ---------------------------------------------------------------------------
// NT GEMM: C[M,N] = A[M,K]*B[N,K]^T, bf16 in, fp32 acc. 128x128 tile, BK=128,
// 4 waves x (4x4 mfma_f32_16x16x32_bf16). Rolled K-loop (R5 codegen — full
// unroll regressed 2x in R7). global_load_lds(16B) staging into UNPADDED LDS
// [128][128]; bank conflicts broken by XOR swizzle: 16B group pos of row r
// holds global group g = pos^(r&7) (swizzle on the global source address;
// LDS dest stays linear base+lane*16 as global_load_lds requires). BK=128
// halves the vmcnt(0)+barrier drains vs BK=64; occupancy is grid-capped at
// 2 blocks/CU (512 blocks / 256 CUs) so the 64KB LDS costs nothing (m132's
// BK=128 occupancy penalty doesn't apply here).
// XCD swizzle: blocks sharing an A row-tile satisfy L==ry (mod 8) -> same XCD.
// MODE 0: K proj — act=elu+1, reduce over d -> kappa[h][t]; NO C write
// MODE 1: V proj — bf16 C + fused per-(chunk,head) num/den sums (each wave's
//         64x64 subtile is exactly one chunk x one head)
// MODE 2: MLP1   — +bias, tanh-gelu -> bf16
// MODE 3: MLP2   — +bias -> fp32 (final output)
// ---------------------------------------------------------------------------
template <int MODE>
__global__ __launch_bounds__(256) void gemm_nt(const bf16* __restrict__ A,
                                               const bf16* __restrict__ B,
                                               void* __restrict__ Cv,
                                               const float* __restrict__ bias,
                                               float* __restrict__ kappa,
                                               float* __restrict__ numbuf,
                                               float* __restrict__ denbuf,
                                               int M, int N, int K) {
    __shared__ bf16 As[128][128];
    __shared__ bf16 Bs[128][128];
    __shared__ float Ksh[4][64];   // MODE 1 only (1KB)

    const int tid  = threadIdx.x;
    // XCD swizzle: L = bx + by*gridX; rx = L / gridY, ry = L % gridY
    const int L    = blockIdx.x + blockIdx.y * gridDim.x;
    const int ry   = L % gridDim.y;
    const int rx   = L / gridDim.y;
    const int bm   = ry * 128;
    const int bn   = rx * 128;
    const int wave = tid >> 6;
    const int lane = tid & 63;
    const int wm   = (wave >> 1) * 64;
    const int wn   = (wave & 1) * 64;
    const int quad = lane >> 4;
    const int m16  = lane & 15;
    const int r7   = m16 & 7;

    f32x4 acc[4][4];
    #pragma unroll
    for (int i = 0; i < 4; ++i)
        #pragma unroll
        for (int j = 0; j < 4; ++j)
            #pragma unroll
            for (int r = 0; r < 4; ++r) acc[i][j][r] = 0.f;

    for (int k0 = 0; k0 < K; k0 += 128) {
        // stage 32KB A + 32KB B: slot s = it*256+tid covers (row=s>>4, pos=s&15);
        // fetch global group g = pos^(row&7) so LDS position pos holds it.
        #pragma unroll
        for (int it = 0; it < 8; ++it) {
            int s = it * 256 + tid;
            int row = s >> 4, pos = s & 15;
            int g = pos ^ (row & 7);
            load_lds16(A + (size_t)(bm + row) * K + k0 + g * 8, &As[row][pos * 8]);
            load_lds16(B + (size_t)(bn + row) * K + k0 + g * 8, &Bs[row][pos * 8]);
        }
        __syncthreads();

        #pragma unroll
        for (int kx = 0; kx < 4; ++kx) {
            const int p = ((kx << 2) + quad) ^ r7;   // swizzled position, 0..15
            shortx8 af[4], bfr[4];
            #pragma unroll
            for (int i = 0; i < 4; ++i)
                af[i] = *(const shortx8*)&As[wm + i * 16 + m16][p * 8];
            #pragma unroll
            for (int j = 0; j < 4; ++j)
                bfr[j] = *(const shortx8*)&Bs[wn + j * 16 + m16][p * 8];
            #pragma unroll
            for (int i = 0; i < 4; ++i)
                #pragma unroll
                for (int j = 0; j < 4; ++j)
                    acc[i][j] = __builtin_amdgcn_mfma_f32_16x16x32_bf16(af[i], bfr[j], acc[i][j], 0, 0, 0);
        }
        __syncthreads();
    }

    if (MODE == 0) {
        // kappa[h][t] = sum_d act(K[t][h*64+d]); wave subtile covers head h fully
        const int h = (bn + wn) >> 6;
        #pragma unroll
        for (int i = 0; i < 4; ++i) {
            #pragma unroll
            for (int r = 0; r < 4; ++r) {
                float s = 0.f;
                #pragma unroll
                for (int j = 0; j < 4; ++j) {
                    float v = acc[i][j][r];
                    s += v > 0.f ? v + 1.f : __expf(v);
                }
                s += __shfl_xor(s, 1);
                s += __shfl_xor(s, 2);
                s += __shfl_xor(s, 4);
                s += __shfl_xor(s, 8);
                if (m16 == 0)
                    kappa[(size_t)h * SEQ + bm + wm + i * 16 + quad * 4 + r] = s;
            }
        }
        return;
    }

    if (MODE == 1) {
        // wave's subtile = chunk c (rows) x head h (cols), both complete
        const int c = (bm + wm) >> 6;
        const int h = (bn + wn) >> 6;
        float kv = kappa[(size_t)h * SEQ + bm + wm + lane];
        Ksh[wave][lane] = kv;       // wave-private LDS row, no barrier needed
        float dsum = kv;
        #pragma unroll
        for (int off = 32; off > 0; off >>= 1) dsum += __shfl_xor(dsum, off);
        if (lane == 0) denbuf[(size_t)h * NC + c] = dsum;

        float s[4] = {0.f, 0.f, 0.f, 0.f};
        #pragma unroll
        for (int i = 0; i < 4; ++i) {
            #pragma unroll
            for (int r = 0; r < 4; ++r) {
                float kr = Ksh[wave][i * 16 + quad * 4 + r];
                #pragma unroll
                for (int j = 0; j < 4; ++j) s[j] += kr * acc[i][j][r];
            }
        }
        #pragma unroll
        for (int j = 0; j < 4; ++j) {
            s[j] += __shfl_xor(s[j], 16);
            s[j] += __shfl_xor(s[j], 32);
        }
        if (quad == 0) {
            size_t nb = ((size_t)h * NC + c) * 64;
            #pragma unroll
            for (int j = 0; j < 4; ++j) numbuf[nb + j * 16 + m16] = s[j];
        }
        // fall through to bf16 V store
    }

    // C/D layout: col = lane&15, row = quad*4 + reg (verified m89/m91)
    #pragma unroll
    for (int i = 0; i < 4; ++i) {
        int row0 = bm + wm + i * 16 + quad * 4;
        #pragma unroll
        for (int j = 0; j < 4; ++j) {
            int col = bn + wn + j * 16 + m16;
            #pragma unroll
            for (int r = 0; r < 4; ++r) {
                float v = acc[i][j][r];
                size_t o = (size_t)(row0 + r) * N + col;
                if (MODE == 1) {
                    ((bf16*)Cv)[o] = __float2bfloat16(v);
                } else if (MODE == 2) {
                    v += bias[col];
                    float t = tanhf(0.7978845608028654f * (v + 0.044715f * v * v * v));
                    ((bf16*)Cv)[o] = __float2bfloat16(0.5f * v * (1.f + t));
                } else {
                    v += bias[col];
                    ((float*)Cv)[o] = v;
                }
            }
        }
    }
}

// ---------------------------------------------------------------------------
// Exclusive prefix over chunks, parallel: one block per head, wave w owns
// chunks [w*32, w*32+32) in registers; cross-wave offsets via LDS.
// ---------------------------------------------------------------------------
__global__ __launch_bounds__(256) void prefix_state(float* __restrict__ numbuf,
                                                    float* __restrict__ denbuf) {
    const int h = blockIdx.x;
    const int wave = threadIdx.x >> 6;
    const int d = threadIdx.x & 63;
    __shared__ float tot[4][64];
    __shared__ float dtot[4];

    float val[32], dval[32];
    const int c0 = wave * 32;
    #pragma unroll
    for (int i = 0; i < 32; ++i) {
        size_t idx = (size_t)h * NC + c0 + i;
        val[i]  = numbuf[idx * 64 + d];
        dval[i] = denbuf[idx];          // broadcast load, all lanes same
    }
    float run = 0.f, drun = 0.f;
    #pragma unroll
    for (int i = 0; i < 32; ++i) {
        float t = val[i];  val[i]  = run;  run  += t;
        float dt = dval[i]; dval[i] = drun; drun += dt;
    }
    tot[wave][d] = run;
    if (d == 0) dtot[wave] = drun;
    __syncthreads();
    float off = 0.f, doff = 0.f;
    for (int w = 0; w < wave; ++w) { off += tot[w][d]; doff += dtot[w]; }
    #pragma unroll
    for (int i = 0; i < 32; ++i) {
        size_t idx = (size_t)h * NC + c0 + i;
        numbuf[idx * 64 + d] = val[i] + off;
        if (d == 0) denbuf[idx] = dval[i] + doff;
    }
}

// ---------------------------------------------------------------------------
// out[t][v] = (Nexcl[v] + sum_{i<=t} kappa_i V[i][v]) / (Dexcl + sum_{i<=t} kappa_i)
// Thread (t = tid>>2, v0 = (tid&3)*16) owns 16 outputs. V is bf16.
// ---------------------------------------------------------------------------
__global__ __launch_bounds__(256) void chunk_out(const bf16* __restrict__ vb,
                                                 const float* __restrict__ kappa,
                                                 const float* __restrict__ numbuf,
                                                 const float* __restrict__ denbuf,
                                                 bf16* __restrict__ out) {
    const int h = blockIdx.x, c = blockIdx.y;
    __shared__ float Ksh[64];
    __shared__ float Vs[64][64];
    const int tid = threadIdx.x;

    #pragma unroll
    for (int it = 0; it < 2; ++it) {
        int s = it * 256 + tid;
        int r = s >> 3, d8 = (s & 7) * 8;
        shortx8 raw = *(const shortx8*)(vb + (size_t)(c * 64 + r) * DM + h * 64 + d8);
        #pragma unroll
        for (int e = 0; e < 8; ++e) Vs[r][d8 + e] = bf2f(raw[e]);
    }
    if (tid < 64) Ksh[tid] = kappa[(size_t)h * SEQ + c * 64 + tid];
    __syncthreads();

    const int t  = tid >> 2;
    const int v0 = (tid & 3) << 4;
    const size_t bidx = (size_t)h * NC + c;

    float den = denbuf[bidx];
    float num[16];
    #pragma unroll
    for (int jj = 0; jj < 4; ++jj) {
        float4 n4 = *(const float4*)&numbuf[bidx * 64 + v0 + jj * 4];
        num[jj * 4 + 0] = n4.x; num[jj * 4 + 1] = n4.y;
        num[jj * 4 + 2] = n4.z; num[jj * 4 + 3] = n4.w;
    }

    for (int i = 0; i <= t; ++i) {
        float s = Ksh[i];
        den += s;
        #pragma unroll
        for (int jj = 0; jj < 4; ++jj) {
            float4 v4 = *(const float4*)&Vs[i][v0 + jj * 4];
            num[jj * 4 + 0] += s * v4.x; num[jj * 4 + 1] += s * v4.y;
            num[jj * 4 + 2] += s * v4.z; num[jj * 4 + 3] += s * v4.w;
        }
    }

    const float inv = 1.0f / den;
    size_t og = (size_t)(c * 64 + t) * DM + h * 64 + v0;
    #pragma unroll
    for (int j = 0; j < 16; ++j) out[og + j] = __float2bfloat16(num[j] * inv);
}

// ---------------------------------------------------------------------------
extern "C" void kernel_launch(void* const* d_in, const int* in_sizes, int n_in,
                              void* d_out, int out_size, void* d_ws, size_t ws_size,
                              hipStream_t stream) {
    const float* xs = (const float*)d_in[0];
    // d_in[1] = wq — provably unused: 'hkv,hq->hv' / 'hk,hq->h' sum k and q
    // independently, so the Sum(qa) factor cancels in sq/zq.
    const float* wk = (const float*)d_in[2];
    const float* wv = (const float*)d_in[3];
    const float* w1 = (const float*)d_in[4];
    const float* b1 = (const float*)d_in[5];
    const float* w2 = (const float*)d_in[6];
    const float* b2 = (const float*)d_in[7];
    float* y = (float*)d_out;

    char* base = (char*)d_ws;
    size_t off = 0;
    auto alloc = [&](size_t b) -> char* {
        char* p = base + off;
        off += (b + 255) & ~(size_t)255;
        return p;
    };

    const size_t NMAT = (size_t)SEQ * DM;      // 8.39M
    const size_t NW   = (size_t)DM * DM;       // 1.05M
    bf16*  xsb    = (bf16*)alloc(NMAT * 2);
    bf16*  wall   = (bf16*)alloc(4 * NW * 2);  // wk|wv|w1|w2, contiguous
    bf16*  wkb    = wall;
    bf16*  wvb    = wall + NW;
    bf16*  w1b    = wall + 2 * NW;
    bf16*  w2b    = wall + 3 * NW;
    bf16*  vb     = (bf16*)alloc(NMAT * 2);    // V bf16
    float* kappa  = (float*)alloc((size_t)NH * SEQ * 4);
    float* numbuf = (float*)alloc((size_t)NH * NC * 64 * 4);
    float* denbuf = (float*)alloc((size_t)NH * NC * 4);
    bf16*  outb   = (bf16*)alloc(NMAT * 2);
    bf16*  hb     = (bf16*)alloc(NMAT * 2);

    // 1. all conversions in one launch (wq skipped)
    {
        size_t total_g = XS_G + 4 * W_G;       // 3,145,728 vec4 groups
        convert_all<<<(int)(total_g / 256), 256, 0, stream>>>(xs, wk, wv, w1, w2,
                                                              xsb, wall);
    }

    // 2. K projection (act + kappa reduction fused, no K stored), then
    //    V projection (bf16 V + fused per-chunk num/den sums)
    dim3 ggrid(DM / 128, SEQ / 128);   // (8, 64)
    gemm_nt<0><<<ggrid, 256, 0, stream>>>(xsb, wkb, nullptr, nullptr, kappa,
                                          nullptr, nullptr, SEQ, DM, DM);
    gemm_nt<1><<<ggrid, 256, 0, stream>>>(xsb, wvb, vb, nullptr, kappa,
                                          numbuf, denbuf, SEQ, DM, DM);

    // 3. exclusive chunk prefix + per-token output
    prefix_state<<<NH, 256, 0, stream>>>(numbuf, denbuf);
    chunk_out<<<dim3(NH, NC), 256, 0, stream>>>(vb, kappa, numbuf, denbuf, outb);

    // 4. MLP
    gemm_nt<2><<<ggrid, 256, 0, stream>>>(outb, w1b, hb, b1, nullptr,
                                          nullptr, nullptr, SEQ, DM, DM);
    gemm_nt<3><<<ggrid, 256, 0, stream>>>(hb, w2b, y, b2, nullptr,
                                          nullptr, nullptr, SEQ, DM, DM);
}

// Round 9
// 229.677 us; speedup vs baseline: 1.2682x; 1.0534x over previous
//
#include <hip/hip_runtime.h>
#include <hip/hip_bf16.h>

using bf16 = __hip_bfloat16;
typedef __attribute__((ext_vector_type(8))) short shortx8;  // 8 bf16 = 4 VGPRs (MFMA A/B frag)
typedef __attribute__((ext_vector_type(4))) float f32x4;    // MFMA C/D frag

#define SEQ 8192
#define DM 1024
#define NH 16
#define CHUNK 64
#define NC (SEQ / CHUNK)   // 128

// async global->LDS, 16B per lane; LDS dest is wave-uniform base + lane*16
__device__ __forceinline__ void load_lds16(const bf16* g, bf16* l) {
    __builtin_amdgcn_global_load_lds(
        (const __attribute__((address_space(1))) void*)g,
        (__attribute__((address_space(3))) void*)l, 16, 0, 0);
}

__device__ __forceinline__ float bf2f(short s) {
    union { unsigned u; float f; } x;
    x.u = ((unsigned)(unsigned short)s) << 16;
    return x.f;
}

// ---------------------------------------------------------------------------
// One-shot fp32 -> bf16 conversion for xs + 4 weight matrices.
// Segment selection is WAVE-UNIFORM via blockIdx ranges (R8's dynamically
// indexed pointer array was lowered to scratch -> 40us latency-bound kernel;
// this version is a pure stream: 16B load / 8B store per thread).
// Blocks 0..8191: xs. Then 4 segments of 1024 blocks: wk, wv, w1, w2.
// ---------------------------------------------------------------------------
__global__ __launch_bounds__(256) void convert_all(const float* __restrict__ xs,
                                                   const float* __restrict__ wk,
                                                   const float* __restrict__ wv,
                                                   const float* __restrict__ w1,
                                                   const float* __restrict__ w2,
                                                   bf16* __restrict__ xsb,
                                                   bf16* __restrict__ wall) {
    const int b = blockIdx.x;
    const float* in;
    bf16* out;
    int blk;                         // block index within segment
    if (b < 8192) {
        in = xs; out = xsb; blk = b;
    } else {
        const int seg = (b - 8192) >> 10;      // 0..3, uniform
        blk = (b - 8192) & 1023;
        out = wall + (size_t)seg * DM * DM;
        if (seg == 0)      in = wk;
        else if (seg == 1) in = wv;
        else if (seg == 2) in = w1;
        else               in = w2;
    }
    size_t i = ((size_t)blk * 256 + threadIdx.x) * 4;
    float4 f = *(const float4*)(in + i);
    out[i + 0] = __float2bfloat16(f.x);
    out[i + 1] = __float2bfloat16(f.y);
    out[i + 2] = __float2bfloat16(f.z);
    out[i + 3] = __float2bfloat16(f.w);
}

// ---------------------------------------------------------------------------
// NT GEMM: C[M,N] = A[M,K]*B[N,K]^T, bf16 in, fp32 acc. 128x128 tile, BK=64,
// 4 waves x (4x4 mfma_f32_16x16x32_bf16). Rolled K-loop (best measured
// codegen: R7 full-unroll regressed 2x; R8 BK=128 neutral). global_load_lds
// (16B) staging into UNPADDED LDS [128][64]; bank conflicts broken by XOR
// swizzle: 16B group pos of row r holds global group g = pos^(r&7) (swizzle
// on the global source address; LDS dest stays linear base+lane*16 as
// global_load_lds requires).
// XCD swizzle: blocks sharing an A row-tile satisfy L==ry (mod 8) -> same XCD.
// MODE 0: K proj — act=elu+1, reduce over d -> kappa[h][t]; NO C write
// MODE 1: V proj — bf16 C + fused per-(chunk,head) num/den sums (each wave's
//         64x64 subtile is exactly one chunk x one head)
// MODE 2: MLP1   — +bias, tanh-gelu -> bf16
// MODE 3: MLP2   — +bias -> fp32 (final output)
// ---------------------------------------------------------------------------
template <int MODE>
__global__ __launch_bounds__(256) void gemm_nt(const bf16* __restrict__ A,
                                               const bf16* __restrict__ B,
                                               void* __restrict__ Cv,
                                               const float* __restrict__ bias,
                                               float* __restrict__ kappa,
                                               float* __restrict__ numbuf,
                                               float* __restrict__ denbuf,
                                               int M, int N, int K) {
    __shared__ bf16 As[128][64];
    __shared__ bf16 Bs[128][64];
    __shared__ float Ksh[4][64];   // MODE 1 only (1KB)

    const int tid  = threadIdx.x;
    // XCD swizzle: L = bx + by*gridX; rx = L / gridY, ry = L % gridY
    const int L    = blockIdx.x + blockIdx.y * gridDim.x;
    const int ry   = L % gridDim.y;
    const int rx   = L / gridDim.y;
    const int bm   = ry * 128;
    const int bn   = rx * 128;
    const int wave = tid >> 6;
    const int lane = tid & 63;
    const int wm   = (wave >> 1) * 64;
    const int wn   = (wave & 1) * 64;
    const int quad = lane >> 4;
    const int m16  = lane & 15;
    const int r7   = m16 & 7;

    f32x4 acc[4][4];
    #pragma unroll
    for (int i = 0; i < 4; ++i)
        #pragma unroll
        for (int j = 0; j < 4; ++j)
            #pragma unroll
            for (int r = 0; r < 4; ++r) acc[i][j][r] = 0.f;

    for (int k0 = 0; k0 < K; k0 += 64) {
        // stage 16KB A + 16KB B: slot s = it*256+tid covers (row=s>>3, pos=s&7);
        // fetch global group g = pos^(row&7) so LDS position pos holds it.
        #pragma unroll
        for (int it = 0; it < 4; ++it) {
            int s = it * 256 + tid;
            int row = s >> 3, pos = s & 7;
            int g = pos ^ (row & 7);
            load_lds16(A + (size_t)(bm + row) * K + k0 + g * 8, &As[row][pos * 8]);
            load_lds16(B + (size_t)(bn + row) * K + k0 + g * 8, &Bs[row][pos * 8]);
        }
        __syncthreads();

        #pragma unroll
        for (int kx = 0; kx < 2; ++kx) {
            const int p = ((kx << 2) + quad) ^ r7;
            shortx8 af[4], bfr[4];
            #pragma unroll
            for (int i = 0; i < 4; ++i)
                af[i] = *(const shortx8*)&As[wm + i * 16 + m16][p * 8];
            #pragma unroll
            for (int j = 0; j < 4; ++j)
                bfr[j] = *(const shortx8*)&Bs[wn + j * 16 + m16][p * 8];
            #pragma unroll
            for (int i = 0; i < 4; ++i)
                #pragma unroll
                for (int j = 0; j < 4; ++j)
                    acc[i][j] = __builtin_amdgcn_mfma_f32_16x16x32_bf16(af[i], bfr[j], acc[i][j], 0, 0, 0);
        }
        __syncthreads();
    }

    if (MODE == 0) {
        // kappa[h][t] = sum_d act(K[t][h*64+d]); wave subtile covers head h fully
        const int h = (bn + wn) >> 6;
        #pragma unroll
        for (int i = 0; i < 4; ++i) {
            #pragma unroll
            for (int r = 0; r < 4; ++r) {
                float s = 0.f;
                #pragma unroll
                for (int j = 0; j < 4; ++j) {
                    float v = acc[i][j][r];
                    s += v > 0.f ? v + 1.f : __expf(v);
                }
                s += __shfl_xor(s, 1);
                s += __shfl_xor(s, 2);
                s += __shfl_xor(s, 4);
                s += __shfl_xor(s, 8);
                if (m16 == 0)
                    kappa[(size_t)h * SEQ + bm + wm + i * 16 + quad * 4 + r] = s;
            }
        }
        return;
    }

    if (MODE == 1) {
        // wave's subtile = chunk c (rows) x head h (cols), both complete
        const int c = (bm + wm) >> 6;
        const int h = (bn + wn) >> 6;
        float kv = kappa[(size_t)h * SEQ + bm + wm + lane];
        Ksh[wave][lane] = kv;       // wave-private LDS row, no barrier needed
        float dsum = kv;
        #pragma unroll
        for (int off = 32; off > 0; off >>= 1) dsum += __shfl_xor(dsum, off);
        if (lane == 0) denbuf[(size_t)h * NC + c] = dsum;

        float s[4] = {0.f, 0.f, 0.f, 0.f};
        #pragma unroll
        for (int i = 0; i < 4; ++i) {
            #pragma unroll
            for (int r = 0; r < 4; ++r) {
                float kr = Ksh[wave][i * 16 + quad * 4 + r];
                #pragma unroll
                for (int j = 0; j < 4; ++j) s[j] += kr * acc[i][j][r];
            }
        }
        #pragma unroll
        for (int j = 0; j < 4; ++j) {
            s[j] += __shfl_xor(s[j], 16);
            s[j] += __shfl_xor(s[j], 32);
        }
        if (quad == 0) {
            size_t nb = ((size_t)h * NC + c) * 64;
            #pragma unroll
            for (int j = 0; j < 4; ++j) numbuf[nb + j * 16 + m16] = s[j];
        }
        // fall through to bf16 V store
    }

    // C/D layout: col = lane&15, row = quad*4 + reg (verified m89/m91)
    #pragma unroll
    for (int i = 0; i < 4; ++i) {
        int row0 = bm + wm + i * 16 + quad * 4;
        #pragma unroll
        for (int j = 0; j < 4; ++j) {
            int col = bn + wn + j * 16 + m16;
            #pragma unroll
            for (int r = 0; r < 4; ++r) {
                float v = acc[i][j][r];
                size_t o = (size_t)(row0 + r) * N + col;
                if (MODE == 1) {
                    ((bf16*)Cv)[o] = __float2bfloat16(v);
                } else if (MODE == 2) {
                    v += bias[col];
                    float t = tanhf(0.7978845608028654f * (v + 0.044715f * v * v * v));
                    ((bf16*)Cv)[o] = __float2bfloat16(0.5f * v * (1.f + t));
                } else {
                    v += bias[col];
                    ((float*)Cv)[o] = v;
                }
            }
        }
    }
}

// ---------------------------------------------------------------------------
// Exclusive prefix over chunks, parallel: one block per head, wave w owns
// chunks [w*32, w*32+32) in registers; cross-wave offsets via LDS.
// ---------------------------------------------------------------------------
__global__ __launch_bounds__(256) void prefix_state(float* __restrict__ numbuf,
                                                    float* __restrict__ denbuf) {
    const int h = blockIdx.x;
    const int wave = threadIdx.x >> 6;
    const int d = threadIdx.x & 63;
    __shared__ float tot[4][64];
    __shared__ float dtot[4];

    float val[32], dval[32];
    const int c0 = wave * 32;
    #pragma unroll
    for (int i = 0; i < 32; ++i) {
        size_t idx = (size_t)h * NC + c0 + i;
        val[i]  = numbuf[idx * 64 + d];
        dval[i] = denbuf[idx];          // broadcast load, all lanes same
    }
    float run = 0.f, drun = 0.f;
    #pragma unroll
    for (int i = 0; i < 32; ++i) {
        float t = val[i];  val[i]  = run;  run  += t;
        float dt = dval[i]; dval[i] = drun; drun += dt;
    }
    tot[wave][d] = run;
    if (d == 0) dtot[wave] = drun;
    __syncthreads();
    float off = 0.f, doff = 0.f;
    for (int w = 0; w < wave; ++w) { off += tot[w][d]; doff += dtot[w]; }
    #pragma unroll
    for (int i = 0; i < 32; ++i) {
        size_t idx = (size_t)h * NC + c0 + i;
        numbuf[idx * 64 + d] = val[i] + off;
        if (d == 0) denbuf[idx] = dval[i] + doff;
    }
}

// ---------------------------------------------------------------------------
// out[t][v] = (Nexcl[v] + sum_{i<=t} kappa_i V[i][v]) / (Dexcl + sum_{i<=t} kappa_i)
// Thread (t = tid>>2, v0 = (tid&3)*16) owns 16 outputs. V is bf16.
// ---------------------------------------------------------------------------
__global__ __launch_bounds__(256) void chunk_out(const bf16* __restrict__ vb,
                                                 const float* __restrict__ kappa,
                                                 const float* __restrict__ numbuf,
                                                 const float* __restrict__ denbuf,
                                                 bf16* __restrict__ out) {
    const int h = blockIdx.x, c = blockIdx.y;
    __shared__ float Ksh[64];
    __shared__ float Vs[64][64];
    const int tid = threadIdx.x;

    #pragma unroll
    for (int it = 0; it < 2; ++it) {
        int s = it * 256 + tid;
        int r = s >> 3, d8 = (s & 7) * 8;
        shortx8 raw = *(const shortx8*)(vb + (size_t)(c * 64 + r) * DM + h * 64 + d8);
        #pragma unroll
        for (int e = 0; e < 8; ++e) Vs[r][d8 + e] = bf2f(raw[e]);
    }
    if (tid < 64) Ksh[tid] = kappa[(size_t)h * SEQ + c * 64 + tid];
    __syncthreads();

    const int t  = tid >> 2;
    const int v0 = (tid & 3) << 4;
    const size_t bidx = (size_t)h * NC + c;

    float den = denbuf[bidx];
    float num[16];
    #pragma unroll
    for (int jj = 0; jj < 4; ++jj) {
        float4 n4 = *(const float4*)&numbuf[bidx * 64 + v0 + jj * 4];
        num[jj * 4 + 0] = n4.x; num[jj * 4 + 1] = n4.y;
        num[jj * 4 + 2] = n4.z; num[jj * 4 + 3] = n4.w;
    }

    for (int i = 0; i <= t; ++i) {
        float s = Ksh[i];
        den += s;
        #pragma unroll
        for (int jj = 0; jj < 4; ++jj) {
            float4 v4 = *(const float4*)&Vs[i][v0 + jj * 4];
            num[jj * 4 + 0] += s * v4.x; num[jj * 4 + 1] += s * v4.y;
            num[jj * 4 + 2] += s * v4.z; num[jj * 4 + 3] += s * v4.w;
        }
    }

    const float inv = 1.0f / den;
    size_t og = (size_t)(c * 64 + t) * DM + h * 64 + v0;
    #pragma unroll
    for (int j = 0; j < 16; ++j) out[og + j] = __float2bfloat16(num[j] * inv);
}

// ---------------------------------------------------------------------------
extern "C" void kernel_launch(void* const* d_in, const int* in_sizes, int n_in,
                              void* d_out, int out_size, void* d_ws, size_t ws_size,
                              hipStream_t stream) {
    const float* xs = (const float*)d_in[0];
    // d_in[1] = wq — provably unused: 'hkv,hq->hv' / 'hk,hq->h' sum k and q
    // independently, so the Sum(qa) factor cancels in sq/zq.
    const float* wk = (const float*)d_in[2];
    const float* wv = (const float*)d_in[3];
    const float* w1 = (const float*)d_in[4];
    const float* b1 = (const float*)d_in[5];
    const float* w2 = (const float*)d_in[6];
    const float* b2 = (const float*)d_in[7];
    float* y = (float*)d_out;

    char* base = (char*)d_ws;
    size_t off = 0;
    auto alloc = [&](size_t b) -> char* {
        char* p = base + off;
        off += (b + 255) & ~(size_t)255;
        return p;
    };

    const size_t NMAT = (size_t)SEQ * DM;      // 8.39M
    const size_t NW   = (size_t)DM * DM;       // 1.05M
    bf16*  xsb    = (bf16*)alloc(NMAT * 2);
    bf16*  wall   = (bf16*)alloc(4 * NW * 2);  // wk|wv|w1|w2, contiguous
    bf16*  wkb    = wall;
    bf16*  wvb    = wall + NW;
    bf16*  w1b    = wall + 2 * NW;
    bf16*  w2b    = wall + 3 * NW;
    bf16*  vb     = (bf16*)alloc(NMAT * 2);    // V bf16
    float* kappa  = (float*)alloc((size_t)NH * SEQ * 4);
    float* numbuf = (float*)alloc((size_t)NH * NC * 64 * 4);
    float* denbuf = (float*)alloc((size_t)NH * NC * 4);
    bf16*  outb   = (bf16*)alloc(NMAT * 2);
    bf16*  hb     = (bf16*)alloc(NMAT * 2);

    // 1. all conversions in one launch (wq skipped); 8192 xs blocks + 4*1024
    convert_all<<<8192 + 4 * 1024, 256, 0, stream>>>(xs, wk, wv, w1, w2,
                                                     xsb, wall);

    // 2. K projection (act + kappa reduction fused, no K stored), then
    //    V projection (bf16 V + fused per-chunk num/den sums)
    dim3 ggrid(DM / 128, SEQ / 128);   // (8, 64)
    gemm_nt<0><<<ggrid, 256, 0, stream>>>(xsb, wkb, nullptr, nullptr, kappa,
                                          nullptr, nullptr, SEQ, DM, DM);
    gemm_nt<1><<<ggrid, 256, 0, stream>>>(xsb, wvb, vb, nullptr, kappa,
                                          numbuf, denbuf, SEQ, DM, DM);

    // 3. exclusive chunk prefix + per-token output
    prefix_state<<<NH, 256, 0, stream>>>(numbuf, denbuf);
    chunk_out<<<dim3(NH, NC), 256, 0, stream>>>(vb, kappa, numbuf, denbuf, outb);

    // 4. MLP
    gemm_nt<2><<<ggrid, 256, 0, stream>>>(outb, w1b, hb, b1, nullptr,
                                          nullptr, nullptr, SEQ, DM, DM);
    gemm_nt<3><<<ggrid, 256, 0, stream>>>(hb, w2b, y, b2, nullptr,
                                          nullptr, nullptr, SEQ, DM, DM);
}